// Round 2
// baseline (527.519 us; speedup 1.0000x reference)
//
#include <hip/hip_runtime.h>

#define N_DATA   128
#define SEG_LEN  131072
#define NPROD    (SEG_LEN - 1)
#define N_MAT    8
#define N_MATP   8
#define N_PROCP  5
#define RGAS     8.314f

#define NCH      64          // chunks per row
#define CHUNK    2048        // elements per chunk
#define TPB      256
#define EPT      8           // CHUNK / TPB

// s(t), algebraically folded to a single reciprocal:
// sigma_ss = (base_num*u*Lg + Sigma0*cbd) / (Lg*(u+cbd)),  u = R*Lg + 1e-9
__device__ __forceinline__ float stress_s(float t,
    float alpha1, float L0, float G200, float Sigma0, float A0,
    float inv_tau, float cbd, float base_num, float R) {
  float Lg  = G200 * __expf(alpha1 * __logf(t * (1.0f / 200.0f) + 0.001f)) + L0;
  float u   = R * Lg + 1e-9f;
  float num = base_num * u * Lg + Sigma0 * cbd;
  float den = Lg * (u + cbd);
  float sigma_ss = num * __builtin_amdgcn_rcpf(den);
  return sigma_ss + A0 * __expf(-t * inv_tau);
}

// Single-pass scan: each block handles one 2048-element chunk of one row.
// Chunk aggregates are published in d_ws as packed {state=1 (hi32), float bits (lo32)};
// 0xAA poison has hi32 == 0xAAAAAAAA != 1, so no initialization pass is needed.
// Wave 0 looks back over <=63 predecessor chunks in parallel (one lane each).
__global__ __launch_bounds__(TPB) void fused_scan(
    const float* __restrict__ x,
    const float* __restrict__ pc,
    const float* __restrict__ raw,
    const float* __restrict__ lb,
    const float* __restrict__ ub,
    const float* __restrict__ sc,
    const int*  __restrict__ mat_idx,
    unsigned long long* __restrict__ agg,
    float* __restrict__ out) {
  __shared__ float rc[16];
  __shared__ float ws4[4];
  __shared__ float ldsP;
  __shared__ float tile[CHUNK + CHUNK / 8];   // 2304 floats, 9.2 KB (pad every 8)

  int b   = blockIdx.x;
  int row = b >> 6;
  int ch  = b & (NCH - 1);
  int tid = threadIdx.x;

  // --- per-block param computation (thread 0 only; 16384x redundancy avoided) ---
  if (tid == 0) {
    auto xv = [&](int i) {
      float s = 1.0f / (1.0f + __expf(-raw[i]));
      return s * (ub[i] - lb[i]) + lb[i];
    };
    int pb = N_MAT * N_MATP + row * N_PROCP;
    float SigmaC = xv(pb + 0), K0 = xv(pb + 1), alpha1 = xv(pb + 2);
    float L0 = xv(pb + 3), G200 = xv(pb + 4);
    int mb = mat_idx[row] * N_MATP;
    float Sigma0 = xv(mb + 0), BetaD = xv(mb + 1), Ea = xv(mb + 2), Mfda = xv(mb + 3);
    float Di = xv(mb + 4), A0 = xv(mb + 5), B0 = xv(mb + 6), l0 = xv(mb + 7);
    float R = pc[row * 4 + 0], T = pc[row * 4 + 1], P = pc[row * 4 + 2];
    rc[0] = alpha1; rc[1] = L0; rc[2] = G200; rc[3] = Sigma0;
    rc[4] = A0;     rc[5] = 1.0f / (B0 * l0 + 1e-9f);
    rc[6] = BetaD * Di * __expf(-Ea / (RGAS * T));      // cbd
    rc[7] = SigmaC - Mfda * P;                          // base_num
    rc[8] = R;      rc[9] = K0;
    rc[10] = sc[0]; rc[11] = sc[1] - sc[0];             // x_min, x_range
    rc[12] = sc[2]; rc[13] = 1.0f / (sc[3] - sc[2]);    // y_min, inv_yrange
  }
  __syncthreads();
  float alpha1 = rc[0], L0 = rc[1], G200 = rc[2], Sigma0 = rc[3], A0 = rc[4];
  float inv_tau = rc[5], cbd = rc[6], base_num = rc[7], R = rc[8], K0 = rc[9];
  float x_min = rc[10], x_sc = rc[11], y_min = rc[12], inv_yr = rc[13];

  // --- load chunk, compute products, thread-local inclusive prefix ---
  long rowbase = (long)row * SEG_LEN;
  int  gbase   = ch * CHUNK + tid * EPT;
  const float* xp = x + rowbase + gbase;

  float4 a  = *(const float4*)xp;
  float4 bq = *(const float4*)(xp + 4);
  float  xn = (gbase + EPT < SEG_LEN) ? xp[EPT] : 0.0f;
  float tv[9];
  tv[0] = a.x  * x_sc + x_min; tv[1] = a.y  * x_sc + x_min;
  tv[2] = a.z  * x_sc + x_min; tv[3] = a.w  * x_sc + x_min;
  tv[4] = bq.x * x_sc + x_min; tv[5] = bq.y * x_sc + x_min;
  tv[6] = bq.z * x_sc + x_min; tv[7] = bq.w * x_sc + x_min;
  tv[8] = xn   * x_sc + x_min;

  float pref[EPT];
  float run = 0.0f;
#pragma unroll
  for (int k = 0; k < EPT; k++) {
    float p = 0.0f;
    if (gbase + k < NPROD) {
      float s = stress_s(tv[k], alpha1, L0, G200, Sigma0, A0, inv_tau, cbd, base_num, R);
      p = s * (tv[k + 1] - tv[k]);
    }
    run += p;
    pref[k] = run;
  }

  // --- wave inclusive scan of thread sums ---
  int lane = tid & 63, wv = tid >> 6;
  float incl = run;
#pragma unroll
  for (int d = 1; d < 64; d <<= 1) {
    float n = __shfl_up(incl, d);
    if (lane >= d) incl += n;
  }
  if (lane == 63) ws4[wv] = incl;
  __syncthreads();

  // --- publish this chunk's aggregate ASAP (before any waiting!) ---
  if (tid == 0) {
    float S = ws4[0] + ws4[1] + ws4[2] + ws4[3];
    unsigned long long packed = (1ULL << 32) | (unsigned long long)__float_as_uint(S);
    __hip_atomic_store(&agg[b], packed, __ATOMIC_RELEASE, __HIP_MEMORY_SCOPE_AGENT);
  }

  // --- wave 0: parallel lookback, lane i <-> predecessor chunk i ---
  if (wv == 0) {
    float pv = 0.0f;
    if (lane < ch) {
      const unsigned long long* slot = &agg[((long)row << 6) + lane];
      unsigned long long v = __hip_atomic_load(slot, __ATOMIC_ACQUIRE, __HIP_MEMORY_SCOPE_AGENT);
      while ((unsigned)(v >> 32) != 1u) {
        __builtin_amdgcn_s_sleep(2);
        v = __hip_atomic_load(slot, __ATOMIC_ACQUIRE, __HIP_MEMORY_SCOPE_AGENT);
      }
      pv = __uint_as_float((unsigned)(v & 0xffffffffu));
    }
#pragma unroll
    for (int d = 32; d > 0; d >>= 1) pv += __shfl_down(pv, d);
    if (lane == 0) ldsP = pv;
  }
  __syncthreads();

  // --- final values: K0 + row-prefix + block-exclusive + thread prefix ---
  float woff = 0.0f;
#pragma unroll
  for (int w = 0; w < 4; w++) woff += (w < wv) ? ws4[w] : 0.0f;
  float excl = incl - run + woff;
  float addv = K0 + ldsP + excl;

#pragma unroll
  for (int k = 0; k < EPT; k++)
    tile[tid * 9 + k] = (addv + pref[k] - y_min) * inv_yr;   // j + (j>>3) with j=tid*8+k
  __syncthreads();

  // --- coalesced store ---
  long obase = rowbase + ch * CHUNK + 1;
#pragma unroll
  for (int k = 0; k < EPT; k++) {
    int j = k * TPB + tid;
    int g = ch * CHUNK + j;
    if (g < NPROD) out[obase + j] = tile[j + (j >> 3)];
  }
  if (ch == 0 && tid == 0) out[rowbase] = (K0 - y_min) * inv_yr;
}

extern "C" void kernel_launch(void* const* d_in, const int* in_sizes, int n_in,
                              void* d_out, int out_size, void* d_ws, size_t ws_size,
                              hipStream_t stream) {
  const float* x_scaled  = (const float*)d_in[0];
  const float* process_c = (const float*)d_in[1];
  const float* raw       = (const float*)d_in[2];
  const float* lb        = (const float*)d_in[3];
  const float* ub        = (const float*)d_in[4];
  const float* sc        = (const float*)d_in[5];
  // d_in[6] = fit_index (unused by the reference computation)
  const int*   mat_idx   = (const int*)d_in[7];
  float* out = (float*)d_out;
  unsigned long long* agg = (unsigned long long*)d_ws;  // 8192 slots x 8 B

  fused_scan<<<N_DATA * NCH, TPB, 0, stream>>>(
      x_scaled, process_c, raw, lb, ub, sc, mat_idx, agg, out);
}

// Round 3
// 201.821 us; speedup vs baseline: 2.6138x; 2.6138x over previous
//
#include <hip/hip_runtime.h>

#define N_DATA   128
#define SEG_LEN  131072
#define NPROD    (SEG_LEN - 1)
#define N_MAT    8
#define N_MATP   8
#define N_PROCP  5
#define RGAS     8.314f

#define TPB      1024
#define EPT      8
#define TILE     (TPB * EPT)        // 8192
#define NITER    (SEG_LEN / TILE)   // 16
#define NWAVE    (TPB / 64)         // 16

// s(t), algebraically folded to a single reciprocal:
// sigma_ss = (base_num*u*Lg + Sigma0*cbd) / (Lg*(u+cbd)),  u = R*Lg + 1e-9
__device__ __forceinline__ float stress_s(float t,
    float alpha1, float L0, float G200, float Sigma0, float A0,
    float inv_tau, float cbd, float base_num, float R) {
  float Lg  = G200 * __expf(alpha1 * __logf(t * (1.0f / 200.0f) + 0.001f)) + L0;
  float u   = R * Lg + 1e-9f;
  float num = base_num * u * Lg + Sigma0 * cbd;
  float den = Lg * (u + cbd);
  float sigma_ss = num * __builtin_amdgcn_rcpf(den);
  return sigma_ss + A0 * __expf(-t * inv_tau);
}

// One block per row. Rolling block-scan: 16 tiles of 8192 elements,
// carry maintained redundantly in every thread (no serial bottleneck).
// Output alignment trick: out[i] = K0 + inclusive_prefix(i-1), so thread t
// stores OUTPUT indices [t*8, t*8+8) = base + {0, pref[0..6]} -> float4-aligned,
// and out[row][0] = K0 emerges naturally from thread 0, tile 0.
__global__ __launch_bounds__(TPB) void row_scan(
    const float* __restrict__ x,
    const float* __restrict__ pc,
    const float* __restrict__ raw,
    const float* __restrict__ lb,
    const float* __restrict__ ub,
    const float* __restrict__ sc,
    const int*  __restrict__ mat_idx,
    float* __restrict__ out) {
  __shared__ float rc[16];
  __shared__ float wtot[2][NWAVE];

  int row = blockIdx.x;
  int tid = threadIdx.x;

  if (tid == 0) {
    auto xv = [&](int i) {
      float s = 1.0f / (1.0f + __expf(-raw[i]));
      return s * (ub[i] - lb[i]) + lb[i];
    };
    int pb = N_MAT * N_MATP + row * N_PROCP;
    float SigmaC = xv(pb + 0), K0 = xv(pb + 1), alpha1 = xv(pb + 2);
    float L0 = xv(pb + 3), G200 = xv(pb + 4);
    int mb = mat_idx[row] * N_MATP;
    float Sigma0 = xv(mb + 0), BetaD = xv(mb + 1), Ea = xv(mb + 2), Mfda = xv(mb + 3);
    float Di = xv(mb + 4), A0 = xv(mb + 5), B0 = xv(mb + 6), l0 = xv(mb + 7);
    float R = pc[row * 4 + 0], T = pc[row * 4 + 1], P = pc[row * 4 + 2];
    rc[0] = alpha1; rc[1] = L0; rc[2] = G200; rc[3] = Sigma0;
    rc[4] = A0;     rc[5] = 1.0f / (B0 * l0 + 1e-9f);
    rc[6] = BetaD * Di * __expf(-Ea / (RGAS * T));      // cbd
    rc[7] = SigmaC - Mfda * P;                          // base_num
    rc[8] = R;      rc[9] = K0;
    rc[10] = sc[0]; rc[11] = sc[1] - sc[0];             // x_min, x_range
    rc[12] = sc[2]; rc[13] = 1.0f / (sc[3] - sc[2]);    // y_min, inv_yrange
  }
  __syncthreads();
  float alpha1 = rc[0], L0 = rc[1], G200 = rc[2], Sigma0 = rc[3], A0 = rc[4];
  float inv_tau = rc[5], cbd = rc[6], base_num = rc[7], R = rc[8], K0 = rc[9];
  float x_min = rc[10], x_sc = rc[11], y_min = rc[12], inv_yr = rc[13];

  int lane = tid & 63, wv = tid >> 6;
  long rowbase = (long)row * SEG_LEN;
  const float* xr = x + rowbase;
  float* outr = out + rowbase;

  float carry = K0;   // thread-local running total (identical in all threads)

  // preload tile 0
  int gb0 = tid * EPT;
  float4 a  = *(const float4*)(xr + gb0);
  float4 bq = *(const float4*)(xr + gb0 + 4);
  float  xn = xr[gb0 + EPT];   // gb0+8 <= 8192 < SEG_LEN always for tile 0

  for (int it = 0; it < NITER; ++it) {
    int gb = it * TILE + tid * EPT;

    float tv[9];
    tv[0] = a.x  * x_sc + x_min; tv[1] = a.y  * x_sc + x_min;
    tv[2] = a.z  * x_sc + x_min; tv[3] = a.w  * x_sc + x_min;
    tv[4] = bq.x * x_sc + x_min; tv[5] = bq.y * x_sc + x_min;
    tv[6] = bq.z * x_sc + x_min; tv[7] = bq.w * x_sc + x_min;
    tv[8] = xn   * x_sc + x_min;

    // software-pipeline: issue next tile's loads before heavy compute
    float4 na, nb; float nxn = 0.0f;
    if (it + 1 < NITER) {
      int ngb = (it + 1) * TILE + tid * EPT;
      na  = *(const float4*)(xr + ngb);
      nb  = *(const float4*)(xr + ngb + 4);
      nxn = (ngb + EPT < SEG_LEN) ? xr[ngb + EPT] : 0.0f;
    }

    // products + thread-local inclusive prefix
    float pref[EPT];
    float run = 0.0f;
#pragma unroll
    for (int k = 0; k < EPT; k++) {
      float p = 0.0f;
      if (gb + k < NPROD) {
        float s = stress_s(tv[k], alpha1, L0, G200, Sigma0, A0, inv_tau, cbd, base_num, R);
        p = s * (tv[k + 1] - tv[k]);
      }
      run += p;
      pref[k] = run;
    }

    // wave-inclusive scan of thread totals
    float incl = run;
#pragma unroll
    for (int d = 1; d < 64; d <<= 1) {
      float n = __shfl_up(incl, d);
      if (lane >= d) incl += n;
    }
    int buf = it & 1;
    if (lane == 63) wtot[buf][wv] = incl;
    __syncthreads();   // single barrier per tile (wtot double-buffered)

    float low = 0.0f, tot = 0.0f;
#pragma unroll
    for (int w = 0; w < NWAVE; w++) {
      float v = wtot[buf][w];
      tot += v;
      low += (w < wv) ? v : 0.0f;
    }

    float base = carry + (incl - run) + low;   // = K0 + incl-prefix(gb-1)
    carry += tot;

    // store output indices [gb, gb+8): base + {0, pref[0..6]}, scaled
    float4 o0, o1;
    o0.x = (base           - y_min) * inv_yr;
    o0.y = (base + pref[0] - y_min) * inv_yr;
    o0.z = (base + pref[1] - y_min) * inv_yr;
    o0.w = (base + pref[2] - y_min) * inv_yr;
    o1.x = (base + pref[3] - y_min) * inv_yr;
    o1.y = (base + pref[4] - y_min) * inv_yr;
    o1.z = (base + pref[5] - y_min) * inv_yr;
    o1.w = (base + pref[6] - y_min) * inv_yr;
    *(float4*)(outr + gb)     = o0;
    *(float4*)(outr + gb + 4) = o1;

    a = na; bq = nb; xn = nxn;
  }
}

extern "C" void kernel_launch(void* const* d_in, const int* in_sizes, int n_in,
                              void* d_out, int out_size, void* d_ws, size_t ws_size,
                              hipStream_t stream) {
  const float* x_scaled  = (const float*)d_in[0];
  const float* process_c = (const float*)d_in[1];
  const float* raw       = (const float*)d_in[2];
  const float* lb        = (const float*)d_in[3];
  const float* ub        = (const float*)d_in[4];
  const float* sc        = (const float*)d_in[5];
  // d_in[6] = fit_index (unused by the reference computation)
  const int*   mat_idx   = (const int*)d_in[7];
  float* out = (float*)d_out;

  row_scan<<<N_DATA, TPB, 0, stream>>>(
      x_scaled, process_c, raw, lb, ub, sc, mat_idx, out);
}

// Round 4
// 192.141 us; speedup vs baseline: 2.7455x; 1.0504x over previous
//
#include <hip/hip_runtime.h>

#define N_DATA   128
#define SEG_LEN  131072
#define NPROD    (SEG_LEN - 1)
#define N_MAT    8
#define N_MATP   8
#define N_PROCP  5
#define RGAS     8.314f

#define NCH      64          // chunks per row (== wave size, deliberate)
#define CHUNK    2048        // elements per chunk
#define TPB      256
#define EPT      8           // CHUNK / TPB

// s(t), algebraically folded to a single reciprocal:
// sigma_ss = (base_num*u*Lg + Sigma0*cbd) / (Lg*(u+cbd)),  u = R*Lg + 1e-9
__device__ __forceinline__ float stress_s(float t,
    float alpha1, float L0, float G200, float Sigma0, float A0,
    float inv_tau, float cbd, float base_num, float R) {
  float Lg  = G200 * __expf(alpha1 * __logf(t * (1.0f / 200.0f) + 0.001f)) + L0;
  float u   = R * Lg + 1e-9f;
  float num = base_num * u * Lg + Sigma0 * cbd;
  float den = Lg * (u + cbd);
  float sigma_ss = num * __builtin_amdgcn_rcpf(den);
  return sigma_ss + A0 * __expf(-t * inv_tau);
}

// Per-block parameter computation: thread 0 -> LDS rc[14]. ~16 sigmoids per
// block, 131k exps total across the grid -- negligible vs the 33M in the main loop.
__device__ __forceinline__ void load_params(int row, int tid,
    const float* __restrict__ pc, const float* __restrict__ raw,
    const float* __restrict__ lb, const float* __restrict__ ub,
    const float* __restrict__ sc, const int* __restrict__ mat_idx,
    float* rc) {
  if (tid == 0) {
    auto xv = [&](int i) {
      float s = 1.0f / (1.0f + __expf(-raw[i]));
      return s * (ub[i] - lb[i]) + lb[i];
    };
    int pb = N_MAT * N_MATP + row * N_PROCP;
    float SigmaC = xv(pb + 0), K0 = xv(pb + 1), alpha1 = xv(pb + 2);
    float L0 = xv(pb + 3), G200 = xv(pb + 4);
    int mb = mat_idx[row] * N_MATP;
    float Sigma0 = xv(mb + 0), BetaD = xv(mb + 1), Ea = xv(mb + 2), Mfda = xv(mb + 3);
    float Di = xv(mb + 4), A0 = xv(mb + 5), B0 = xv(mb + 6), l0 = xv(mb + 7);
    float R = pc[row * 4 + 0], T = pc[row * 4 + 1], P = pc[row * 4 + 2];
    rc[0] = alpha1; rc[1] = L0; rc[2] = G200; rc[3] = Sigma0;
    rc[4] = A0;     rc[5] = 1.0f / (B0 * l0 + 1e-9f);
    rc[6] = BetaD * Di * __expf(-Ea / (RGAS * T));      // cbd
    rc[7] = SigmaC - Mfda * P;                          // base_num
    rc[8] = R;      rc[9] = K0;
    rc[10] = sc[0]; rc[11] = sc[1] - sc[0];             // x_min, x_range
    rc[12] = sc[2]; rc[13] = 1.0f / (sc[3] - sc[2]);    // y_min, inv_yrange
  }
}

__global__ __launch_bounds__(TPB) void k1_chunksums(
    const float* __restrict__ x,
    const float* __restrict__ pc, const float* __restrict__ raw,
    const float* __restrict__ lb, const float* __restrict__ ub,
    const float* __restrict__ sc, const int* __restrict__ mat_idx,
    float* __restrict__ chunksum) {
  __shared__ float rc[14];
  __shared__ float ws4[4];

  int b   = blockIdx.x;
  int row = b >> 6;
  int ch  = b & (NCH - 1);
  int tid = threadIdx.x;

  load_params(row, tid, pc, raw, lb, ub, sc, mat_idx, rc);
  __syncthreads();
  float alpha1 = rc[0], L0 = rc[1], G200 = rc[2], Sigma0 = rc[3], A0 = rc[4];
  float inv_tau = rc[5], cbd = rc[6], base_num = rc[7], R = rc[8];
  float x_min = rc[10], x_sc = rc[11];

  long rowbase = (long)row * SEG_LEN;
  int  gbase   = ch * CHUNK + tid * EPT;
  const float* xp = x + rowbase + gbase;

  float4 a  = *(const float4*)xp;
  float4 bq = *(const float4*)(xp + 4);
  float  xn = (gbase + EPT < SEG_LEN) ? xp[EPT] : 0.0f;
  float tv[9];
  tv[0] = a.x  * x_sc + x_min; tv[1] = a.y  * x_sc + x_min;
  tv[2] = a.z  * x_sc + x_min; tv[3] = a.w  * x_sc + x_min;
  tv[4] = bq.x * x_sc + x_min; tv[5] = bq.y * x_sc + x_min;
  tv[6] = bq.z * x_sc + x_min; tv[7] = bq.w * x_sc + x_min;
  tv[8] = xn   * x_sc + x_min;

  float sum = 0.0f;
#pragma unroll
  for (int k = 0; k < EPT; k++) {
    if (gbase + k < NPROD) {
      float s = stress_s(tv[k], alpha1, L0, G200, Sigma0, A0, inv_tau, cbd, base_num, R);
      sum += s * (tv[k + 1] - tv[k]);
    }
  }

  int lane = tid & 63, wv = tid >> 6;
#pragma unroll
  for (int d = 32; d > 0; d >>= 1) sum += __shfl_down(sum, d);
  if (lane == 0) ws4[wv] = sum;
  __syncthreads();
  if (tid == 0) chunksum[row * NCH + ch] = ws4[0] + ws4[1] + ws4[2] + ws4[3];
}

__global__ __launch_bounds__(TPB) void k2_scan_store(
    const float* __restrict__ x,
    const float* __restrict__ pc, const float* __restrict__ raw,
    const float* __restrict__ lb, const float* __restrict__ ub,
    const float* __restrict__ sc, const int* __restrict__ mat_idx,
    const float* __restrict__ chunksum,
    float* __restrict__ out) {
  __shared__ float rc[14];
  __shared__ float wtot[4];

  int b   = blockIdx.x;
  int row = b >> 6;
  int ch  = b & (NCH - 1);
  int tid = threadIdx.x;
  int lane = tid & 63, wv = tid >> 6;

  load_params(row, tid, pc, raw, lb, ub, sc, mat_idx, rc);

  // Each wave redundantly scans its row's 64 chunk sums (L2-hot, 64 == wave size).
  float csv = chunksum[row * NCH + lane];
  float cincl = csv;
#pragma unroll
  for (int d = 1; d < 64; d <<= 1) {
    float n = __shfl_up(cincl, d);
    if (lane >= d) cincl += n;
  }
  float choff = __shfl(cincl - csv, ch);   // exclusive prefix of chunk ch

  __syncthreads();
  float alpha1 = rc[0], L0 = rc[1], G200 = rc[2], Sigma0 = rc[3], A0 = rc[4];
  float inv_tau = rc[5], cbd = rc[6], base_num = rc[7], R = rc[8], K0 = rc[9];
  float x_min = rc[10], x_sc = rc[11], y_min = rc[12], inv_yr = rc[13];

  long rowbase = (long)row * SEG_LEN;
  int  gbase   = ch * CHUNK + tid * EPT;
  const float* xp = x + rowbase + gbase;

  float4 a  = *(const float4*)xp;
  float4 bq = *(const float4*)(xp + 4);
  float  xn = (gbase + EPT < SEG_LEN) ? xp[EPT] : 0.0f;
  float tv[9];
  tv[0] = a.x  * x_sc + x_min; tv[1] = a.y  * x_sc + x_min;
  tv[2] = a.z  * x_sc + x_min; tv[3] = a.w  * x_sc + x_min;
  tv[4] = bq.x * x_sc + x_min; tv[5] = bq.y * x_sc + x_min;
  tv[6] = bq.z * x_sc + x_min; tv[7] = bq.w * x_sc + x_min;
  tv[8] = xn   * x_sc + x_min;

  float pref[EPT];
  float run = 0.0f;
#pragma unroll
  for (int k = 0; k < EPT; k++) {
    float p = 0.0f;
    if (gbase + k < NPROD) {
      float s = stress_s(tv[k], alpha1, L0, G200, Sigma0, A0, inv_tau, cbd, base_num, R);
      p = s * (tv[k + 1] - tv[k]);
    }
    run += p;
    pref[k] = run;   // inclusive within thread
  }

  // wave inclusive scan of thread totals
  float incl = run;
#pragma unroll
  for (int d = 1; d < 64; d <<= 1) {
    float n = __shfl_up(incl, d);
    if (lane >= d) incl += n;
  }
  if (lane == 63) wtot[wv] = incl;
  __syncthreads();
  float low = 0.0f;
#pragma unroll
  for (int w = 0; w < 4; w++) low += (w < wv) ? wtot[w] : 0.0f;

  // out[i] = K0 + inclusive_prefix(i-1); thread t stores output [gbase, gbase+8)
  // = base + {0, pref[0..6]} -> two aligned float4 stores, fully coalesced.
  float base = K0 + choff + (incl - run) + low;
  float4 o0, o1;
  o0.x = (base           - y_min) * inv_yr;
  o0.y = (base + pref[0] - y_min) * inv_yr;
  o0.z = (base + pref[1] - y_min) * inv_yr;
  o0.w = (base + pref[2] - y_min) * inv_yr;
  o1.x = (base + pref[3] - y_min) * inv_yr;
  o1.y = (base + pref[4] - y_min) * inv_yr;
  o1.z = (base + pref[5] - y_min) * inv_yr;
  o1.w = (base + pref[6] - y_min) * inv_yr;
  float* op = out + rowbase + gbase;
  *(float4*)op       = o0;
  *(float4*)(op + 4) = o1;
}

extern "C" void kernel_launch(void* const* d_in, const int* in_sizes, int n_in,
                              void* d_out, int out_size, void* d_ws, size_t ws_size,
                              hipStream_t stream) {
  const float* x_scaled  = (const float*)d_in[0];
  const float* process_c = (const float*)d_in[1];
  const float* raw       = (const float*)d_in[2];
  const float* lb        = (const float*)d_in[3];
  const float* ub        = (const float*)d_in[4];
  const float* sc        = (const float*)d_in[5];
  // d_in[6] = fit_index (unused by the reference computation)
  const int*   mat_idx   = (const int*)d_in[7];
  float* out = (float*)d_out;
  float* chunksum = (float*)d_ws;   // 8192 floats

  k1_chunksums<<<N_DATA * NCH, TPB, 0, stream>>>(
      x_scaled, process_c, raw, lb, ub, sc, mat_idx, chunksum);
  k2_scan_store<<<N_DATA * NCH, TPB, 0, stream>>>(
      x_scaled, process_c, raw, lb, ub, sc, mat_idx, chunksum, out);
}

// Round 6
// 180.536 us; speedup vs baseline: 2.9220x; 1.0643x over previous
//
#include <hip/hip_runtime.h>

#define N_DATA   128
#define SEG_LEN  131072
#define NPROD    (SEG_LEN - 1)
#define N_MAT    8
#define N_MATP   8
#define N_PROCP  5
#define RGAS     8.314f

#define NCH      64          // chunks per row (== wave size, deliberate)
#define CHUNK    2048        // elements per chunk
#define TPB      256
#define EPT      8           // CHUNK / TPB

// sigma_ss = (base_num*u*Lg + Sigma0*cbd) / (Lg*(u+cbd)),  u = R*Lg + 1e-9
__device__ __forceinline__ float stress_s(float t,
    float alpha1, float L0, float G200, float Sigma0, float A0,
    float inv_tau, float cbd, float base_num, float R) {
  float Lg  = G200 * __expf(alpha1 * __logf(t * (1.0f / 200.0f) + 0.001f)) + L0;
  float u   = R * Lg + 1e-9f;
  float num = base_num * u * Lg + Sigma0 * cbd;
  float den = Lg * (u + cbd);
  float sigma_ss = num * __builtin_amdgcn_rcpf(den);
  return sigma_ss + A0 * __expf(-t * inv_tau);
}

// K1: the ONLY compute pass. Products + block scan; stores PROVISIONAL output
// (missing the row-level chunk offset) and the chunk total (pre-scaled by
// inv_yr) for K2's linear fixup. Params computed in parallel (13 threads, one
// sigmoid each, one barrier); x loads issued before the barrier.
__global__ __launch_bounds__(TPB) void k1_compute(
    const float* __restrict__ x,
    const float* __restrict__ pc, const float* __restrict__ raw,
    const float* __restrict__ lb, const float* __restrict__ ub,
    const float* __restrict__ sc, const int* __restrict__ mat_idx,
    float* __restrict__ chunksum_s,
    float* __restrict__ out) {
  __shared__ float pv[13];
  __shared__ float ws4[4];

  int b   = blockIdx.x;
  int row = b >> 6;
  int ch  = b & (NCH - 1);
  int tid = threadIdx.x;
  int lane = tid & 63, wv = tid >> 6;

  // issue the chunk's x loads immediately (don't wait for params)
  long rowbase = (long)row * SEG_LEN;
  int  gb = ch * CHUNK + tid * EPT;
  const float* xp = x + rowbase + gb;
  float4 a  = *(const float4*)xp;
  float4 bq = *(const float4*)(xp + 4);
  float  xn = (gb + EPT < SEG_LEN) ? xp[EPT] : 0.0f;

  // parallel param transform: thread i<13 computes one sigmoid-bounded param
  if (tid < 13) {
    int idx = (tid < 5) ? (N_MAT * N_MATP + row * N_PROCP + tid)
                        : (mat_idx[row] * N_MATP + (tid - 5));
    float s = 1.0f / (1.0f + __expf(-raw[idx]));
    pv[tid] = s * (ub[idx] - lb[idx]) + lb[idx];
  }
  __syncthreads();

  // derived constants, redundantly per-thread (1 extra exp/thread: ~6% of main loop)
  float SigmaC = pv[0], K0 = pv[1], alpha1 = pv[2], L0 = pv[3], G200 = pv[4];
  float Sigma0 = pv[5], BetaD = pv[6], Ea = pv[7], Mfda = pv[8], Di = pv[9];
  float A0 = pv[10], B0 = pv[11], l0 = pv[12];
  float R = pc[row * 4 + 0], T = pc[row * 4 + 1], P = pc[row * 4 + 2];
  float cbd      = BetaD * Di * __expf(-Ea / (RGAS * T));
  float base_num = SigmaC - Mfda * P;
  float inv_tau  = 1.0f / (B0 * l0 + 1e-9f);
  float x_min = sc[0], x_sc = sc[1] - sc[0];
  float y_min = sc[2], inv_yr = 1.0f / (sc[3] - sc[2]);

  float tv[9];
  tv[0] = a.x  * x_sc + x_min; tv[1] = a.y  * x_sc + x_min;
  tv[2] = a.z  * x_sc + x_min; tv[3] = a.w  * x_sc + x_min;
  tv[4] = bq.x * x_sc + x_min; tv[5] = bq.y * x_sc + x_min;
  tv[6] = bq.z * x_sc + x_min; tv[7] = bq.w * x_sc + x_min;
  tv[8] = xn   * x_sc + x_min;

  float pref[EPT];
  float run = 0.0f;
#pragma unroll
  for (int k = 0; k < EPT; k++) {
    float p = 0.0f;
    if (gb + k < NPROD) {
      float s = stress_s(tv[k], alpha1, L0, G200, Sigma0, A0, inv_tau, cbd, base_num, R);
      p = s * (tv[k + 1] - tv[k]);
    }
    run += p;
    pref[k] = run;   // inclusive within thread
  }

  // wave inclusive scan of thread totals
  float incl = run;
#pragma unroll
  for (int d = 1; d < 64; d <<= 1) {
    float n = __shfl_up(incl, d);
    if (lane >= d) incl += n;
  }
  if (lane == 63) ws4[wv] = incl;
  __syncthreads();
  float low = 0.0f, tot = 0.0f;
#pragma unroll
  for (int w = 0; w < 4; w++) {
    float v = ws4[w];
    tot += v;
    low += (w < wv) ? v : 0.0f;
  }
  float texcl = (incl - run) + low;     // chunk-local exclusive prefix

  if (tid == 0) chunksum_s[b] = tot * inv_yr;   // pre-scaled chunk total

  // provisional out[i] = (K0 + chunk-local prefix(i-1) - y_min) * inv_yr
  // thread t covers output indices [gb, gb+8) = base + {0, pref[0..6]}
  float base = K0 + texcl;
  float4 o0, o1;
  o0.x = (base           - y_min) * inv_yr;
  o0.y = (base + pref[0] - y_min) * inv_yr;
  o0.z = (base + pref[1] - y_min) * inv_yr;
  o0.w = (base + pref[2] - y_min) * inv_yr;
  o1.x = (base + pref[3] - y_min) * inv_yr;
  o1.y = (base + pref[4] - y_min) * inv_yr;
  o1.z = (base + pref[5] - y_min) * inv_yr;
  o1.w = (base + pref[6] - y_min) * inv_yr;
  float* op = out + rowbase + gb;
  *(float4*)op       = o0;
  *(float4*)(op + 4) = o1;
}

// K2: pure linear fixup. Each wave scans its row's 64 pre-scaled chunk totals
// in-register (256B coalesced, L2-hot), adds the exclusive prefix for this
// block's chunk to 8 consecutive floats. No transcendentals, memory-bound.
__global__ __launch_bounds__(TPB) void k2_fixup(
    const float* __restrict__ chunksum_s,
    float* __restrict__ out) {
  int b   = blockIdx.x;
  int row = b >> 6;
  int ch  = b & (NCH - 1);
  int tid = threadIdx.x;
  int lane = tid & 63;

  float v = chunksum_s[(row << 6) | lane];
  float incl = v;
#pragma unroll
  for (int d = 1; d < 64; d <<= 1) {
    float n = __shfl_up(incl, d);
    if (lane >= d) incl += n;
  }
  float add = __shfl(incl - v, ch);   // scaled exclusive chunk offset (0 for ch==0)

  long base = (long)row * SEG_LEN + ch * CHUNK + tid * EPT;
  float4 o0 = *(float4*)(out + base);
  float4 o1 = *(float4*)(out + base + 4);
  o0.x += add; o0.y += add; o0.z += add; o0.w += add;
  o1.x += add; o1.y += add; o1.z += add; o1.w += add;
  *(float4*)(out + base)     = o0;
  *(float4*)(out + base + 4) = o1;
}

extern "C" void kernel_launch(void* const* d_in, const int* in_sizes, int n_in,
                              void* d_out, int out_size, void* d_ws, size_t ws_size,
                              hipStream_t stream) {
  const float* x_scaled  = (const float*)d_in[0];
  const float* process_c = (const float*)d_in[1];
  const float* raw       = (const float*)d_in[2];
  const float* lb        = (const float*)d_in[3];
  const float* ub        = (const float*)d_in[4];
  const float* sc        = (const float*)d_in[5];
  // d_in[6] = fit_index (unused by the reference computation)
  const int*   mat_idx   = (const int*)d_in[7];
  float* out = (float*)d_out;
  float* chunksum_s = (float*)d_ws;   // 8192 floats, fully rewritten every launch

  k1_compute<<<N_DATA * NCH, TPB, 0, stream>>>(
      x_scaled, process_c, raw, lb, ub, sc, mat_idx, chunksum_s, out);
  k2_fixup<<<N_DATA * NCH, TPB, 0, stream>>>(chunksum_s, out);
}

// Round 8
// 180.189 us; speedup vs baseline: 2.9276x; 1.0019x over previous
//
#include <hip/hip_runtime.h>

#define N_DATA   128
#define SEG_LEN  131072
#define NPROD    (SEG_LEN - 1)
#define N_MAT    8
#define N_MATP   8
#define N_PROCP  5
#define RGAS     8.314f

#define NCH      64          // chunks per row (== wave size, deliberate)
#define CHUNK    2048        // elements per chunk
#define TPB      256
#define EPT      8           // CHUNK / TPB

typedef float nt4 __attribute__((ext_vector_type(4)));  // native vec for nontemporal builtin

// sigma_ss = (base_num*u*Lg + Sigma0*cbd) / (Lg*(u+cbd)),  u = R*Lg + 1e-9
__device__ __forceinline__ float stress_s(float t,
    float alpha1, float L0, float G200, float Sigma0, float A0,
    float inv_tau, float cbd, float base_num, float R) {
  float Lg  = G200 * __expf(alpha1 * __logf(t * (1.0f / 200.0f) + 0.001f)) + L0;
  float u   = R * Lg + 1e-9f;
  float num = base_num * u * Lg + Sigma0 * cbd;
  float den = Lg * (u + cbd);
  float sigma_ss = num * __builtin_amdgcn_rcpf(den);
  return sigma_ss + A0 * __expf(-t * inv_tau);
}

// Parallel param transform (R6-proven): threads 0..12 compute one sigmoid each
// into LDS; everyone derives the folded constants after one barrier.
// K1: chunk sums ONLY (no output write). Compute-bound.
__global__ __launch_bounds__(TPB) void k1_sums(
    const float* __restrict__ x,
    const float* __restrict__ pc, const float* __restrict__ raw,
    const float* __restrict__ lb, const float* __restrict__ ub,
    const float* __restrict__ sc, const int* __restrict__ mat_idx,
    float* __restrict__ chunksum) {
  __shared__ float pv[13];
  __shared__ float ws4[4];

  int b   = blockIdx.x;
  int row = b >> 6;
  int ch  = b & (NCH - 1);
  int tid = threadIdx.x;
  int lane = tid & 63, wv = tid >> 6;

  // issue x loads immediately (fly during param compute)
  long rowbase = (long)row * SEG_LEN;
  int  gb = ch * CHUNK + tid * EPT;
  const float* xp = x + rowbase + gb;
  float4 a  = *(const float4*)xp;
  float4 bq = *(const float4*)(xp + 4);
  float  xn = (gb + EPT < SEG_LEN) ? xp[EPT] : 0.0f;

  if (tid < 13) {
    int idx = (tid < 5) ? (N_MAT * N_MATP + row * N_PROCP + tid)
                        : (mat_idx[row] * N_MATP + (tid - 5));
    float s = 1.0f / (1.0f + __expf(-raw[idx]));
    pv[tid] = s * (ub[idx] - lb[idx]) + lb[idx];
  }
  __syncthreads();

  float SigmaC = pv[0], alpha1 = pv[2], L0 = pv[3], G200 = pv[4];
  float Sigma0 = pv[5], BetaD = pv[6], Ea = pv[7], Mfda = pv[8], Di = pv[9];
  float A0 = pv[10], B0 = pv[11], l0 = pv[12];
  float R = pc[row * 4 + 0], T = pc[row * 4 + 1], P = pc[row * 4 + 2];
  float cbd      = BetaD * Di * __expf(-Ea / (RGAS * T));
  float base_num = SigmaC - Mfda * P;
  float inv_tau  = 1.0f / (B0 * l0 + 1e-9f);
  float x_min = sc[0], x_sc = sc[1] - sc[0];

  float tv[9];
  tv[0] = a.x  * x_sc + x_min; tv[1] = a.y  * x_sc + x_min;
  tv[2] = a.z  * x_sc + x_min; tv[3] = a.w  * x_sc + x_min;
  tv[4] = bq.x * x_sc + x_min; tv[5] = bq.y * x_sc + x_min;
  tv[6] = bq.z * x_sc + x_min; tv[7] = bq.w * x_sc + x_min;
  tv[8] = xn   * x_sc + x_min;

  float sum = 0.0f;
#pragma unroll
  for (int k = 0; k < EPT; k++) {
    if (gb + k < NPROD) {
      float s = stress_s(tv[k], alpha1, L0, G200, Sigma0, A0, inv_tau, cbd, base_num, R);
      sum += s * (tv[k + 1] - tv[k]);
    }
  }

#pragma unroll
  for (int d = 32; d > 0; d >>= 1) sum += __shfl_down(sum, d);
  if (lane == 0) ws4[wv] = sum;
  __syncthreads();
  if (tid == 0) chunksum[b] = ws4[0] + ws4[1] + ws4[2] + ws4[3];
}

// K2: recompute products once more, add row-level chunk offset (wave-scanned
// in-register from L2-hot chunk sums), write FINAL output with the alignment
// trick (out[i] = K0 + prefix(i-1) -> two aligned float4 nontemporal stores).
__global__ __launch_bounds__(TPB) void k2_write(
    const float* __restrict__ x,
    const float* __restrict__ pc, const float* __restrict__ raw,
    const float* __restrict__ lb, const float* __restrict__ ub,
    const float* __restrict__ sc, const int* __restrict__ mat_idx,
    const float* __restrict__ chunksum,
    float* __restrict__ out) {
  __shared__ float pv[13];
  __shared__ float wtot[4];

  int b   = blockIdx.x;
  int row = b >> 6;
  int ch  = b & (NCH - 1);
  int tid = threadIdx.x;
  int lane = tid & 63, wv = tid >> 6;

  // issue x + chunksum loads immediately
  long rowbase = (long)row * SEG_LEN;
  int  gb = ch * CHUNK + tid * EPT;
  const float* xp = x + rowbase + gb;
  float4 a  = *(const float4*)xp;
  float4 bq = *(const float4*)(xp + 4);
  float  xn = (gb + EPT < SEG_LEN) ? xp[EPT] : 0.0f;
  float csv = chunksum[(row << 6) | lane];

  if (tid < 13) {
    int idx = (tid < 5) ? (N_MAT * N_MATP + row * N_PROCP + tid)
                        : (mat_idx[row] * N_MATP + (tid - 5));
    float s = 1.0f / (1.0f + __expf(-raw[idx]));
    pv[tid] = s * (ub[idx] - lb[idx]) + lb[idx];
  }

  // wave-scan row's 64 chunk sums (no barrier needed; wave-synchronous)
  float cincl = csv;
#pragma unroll
  for (int d = 1; d < 64; d <<= 1) {
    float n = __shfl_up(cincl, d);
    if (lane >= d) cincl += n;
  }
  float choff = __shfl(cincl - csv, ch);   // exclusive prefix of this chunk

  __syncthreads();
  float SigmaC = pv[0], K0 = pv[1], alpha1 = pv[2], L0 = pv[3], G200 = pv[4];
  float Sigma0 = pv[5], BetaD = pv[6], Ea = pv[7], Mfda = pv[8], Di = pv[9];
  float A0 = pv[10], B0 = pv[11], l0 = pv[12];
  float R = pc[row * 4 + 0], T = pc[row * 4 + 1], P = pc[row * 4 + 2];
  float cbd      = BetaD * Di * __expf(-Ea / (RGAS * T));
  float base_num = SigmaC - Mfda * P;
  float inv_tau  = 1.0f / (B0 * l0 + 1e-9f);
  float x_min = sc[0], x_sc = sc[1] - sc[0];
  float y_min = sc[2], inv_yr = 1.0f / (sc[3] - sc[2]);

  float tv[9];
  tv[0] = a.x  * x_sc + x_min; tv[1] = a.y  * x_sc + x_min;
  tv[2] = a.z  * x_sc + x_min; tv[3] = a.w  * x_sc + x_min;
  tv[4] = bq.x * x_sc + x_min; tv[5] = bq.y * x_sc + x_min;
  tv[6] = bq.z * x_sc + x_min; tv[7] = bq.w * x_sc + x_min;
  tv[8] = xn   * x_sc + x_min;

  float pref[EPT];
  float run = 0.0f;
#pragma unroll
  for (int k = 0; k < EPT; k++) {
    float p = 0.0f;
    if (gb + k < NPROD) {
      float s = stress_s(tv[k], alpha1, L0, G200, Sigma0, A0, inv_tau, cbd, base_num, R);
      p = s * (tv[k + 1] - tv[k]);
    }
    run += p;
    pref[k] = run;   // inclusive within thread
  }

  float incl = run;
#pragma unroll
  for (int d = 1; d < 64; d <<= 1) {
    float n = __shfl_up(incl, d);
    if (lane >= d) incl += n;
  }
  if (lane == 63) wtot[wv] = incl;
  __syncthreads();
  float low = 0.0f;
#pragma unroll
  for (int w = 0; w < 4; w++) low += (w < wv) ? wtot[w] : 0.0f;

  float base = K0 + choff + (incl - run) + low;
  nt4 o0, o1;
  o0.x = (base           - y_min) * inv_yr;
  o0.y = (base + pref[0] - y_min) * inv_yr;
  o0.z = (base + pref[1] - y_min) * inv_yr;
  o0.w = (base + pref[2] - y_min) * inv_yr;
  o1.x = (base + pref[3] - y_min) * inv_yr;
  o1.y = (base + pref[4] - y_min) * inv_yr;
  o1.z = (base + pref[5] - y_min) * inv_yr;
  o1.w = (base + pref[6] - y_min) * inv_yr;
  nt4* op = (nt4*)(out + rowbase + gb);
  __builtin_nontemporal_store(o0, op);       // out never re-read: bypass caches,
  __builtin_nontemporal_store(o1, op + 1);   // preserve x's L3 residency
}

extern "C" void kernel_launch(void* const* d_in, const int* in_sizes, int n_in,
                              void* d_out, int out_size, void* d_ws, size_t ws_size,
                              hipStream_t stream) {
  const float* x_scaled  = (const float*)d_in[0];
  const float* process_c = (const float*)d_in[1];
  const float* raw       = (const float*)d_in[2];
  const float* lb        = (const float*)d_in[3];
  const float* ub        = (const float*)d_in[4];
  const float* sc        = (const float*)d_in[5];
  // d_in[6] = fit_index (unused by the reference computation)
  const int*   mat_idx   = (const int*)d_in[7];
  float* out = (float*)d_out;
  float* chunksum = (float*)d_ws;   // 8192 floats, fully rewritten every launch

  k1_sums<<<N_DATA * NCH, TPB, 0, stream>>>(
      x_scaled, process_c, raw, lb, ub, sc, mat_idx, chunksum);
  k2_write<<<N_DATA * NCH, TPB, 0, stream>>>(
      x_scaled, process_c, raw, lb, ub, sc, mat_idx, chunksum, out);
}